// Round 15
// baseline (198.274 us; speedup 1.0000x reference)
//
#include <hip/hip_runtime.h>
#include <hip/hip_fp16.h>

// Problem constants (from reference)
#define BATCH 2
#define NS 128        // input spatial dim (X=Y=Z=128)
#define NB 64         // bricks per dim (fallback path)
#define ND 96         // output grid per spatial dim

constexpr int PPB   = ND * ND * ND;            // 884736 points per batch
constexpr int HPPB  = PPB / 2;                 // 442368
constexpr int TOTAL = BATCH * PPB;             // 1769472
constexpr int BRICKS_PER_BATCH = NB * NB * NB; // 262144
constexpr int TOTAL_BRICKS = BATCH * BRICKS_PER_BATCH;
constexpr size_t WS_BRICKS = (size_t)TOTAL_BRICKS * 64;            // 33.55 MB
constexpr int ENTRIES_PER_BATCH = NS * NS * NS;                    // 2097152
constexpr size_t WS_R4 = (size_t)BATCH * ENTRIES_PER_BATCH * 32;   // 134.2 MB

// native clang vector types: accepted by __builtin_nontemporal_*
typedef float        fx4 __attribute__((ext_vector_type(4)));
typedef unsigned int ux4 __attribute__((ext_vector_type(4)));

__device__ __forceinline__ float4 f4_lerp(float4 a, float4 b, float t) {
    float4 r;
    r.x = fmaf(b.x - a.x, t, a.x);
    r.y = fmaf(b.y - a.y, t, a.y);
    r.z = fmaf(b.z - a.z, t, a.z);
    r.w = fmaf(b.w - a.w, t, a.w);
    return r;
}

__device__ __forceinline__ uint2 pack_h4(float x, float y, float z, float w) {
    __half2 h0 = __float22half2_rn(make_float2(x, y));
    __half2 h1 = __float22half2_rn(make_float2(z, w));
    uint2 p;
    p.x = *(const unsigned int*)&h0;
    p.y = *(const unsigned int*)&h1;
    return p;
}

__device__ __forceinline__ float4 unpack_h4(unsigned int a, unsigned int b) {
    float2 f0 = __half22float2(*(const __half2*)&a);
    float2 f1 = __half22float2(*(const __half2*)&b);
    return make_float4(f0.x, f0.y, f1.x, f1.y);
}

// =====================================================================
// R4 table: per-voxel (x,y) 2x2 neighborhood, 32B/entry, Z FASTEST.
// entry(b,x,y,z): lo = [(x,y)|(x+1',y)], hi = [(x,y+1')|(x+1',y+1')]
// with x+1' = min(x+1,127), y+1' = min(y+1,127) (replicate baked in).
// Entry index == builder thread id: g = b*2^21 + x*2^14 + y*2^7 + z.
// Builder reads (4 z-contiguous streams, L2-reused 4x) stay cached;
// table WRITES are non-temporal so the 132 MB store stream doesn't
// evict the input reuse window from L2.
// =====================================================================
__global__ __launch_bounds__(256) void build_r4_table(
    const fx4* __restrict__ in, ux4* __restrict__ tab)
{
    int g = blockIdx.x * 256 + threadIdx.x;   // grid exact: 4194304 threads
    int z = g & 127;
    int y = (g >> 7) & 127;
    int x = (g >> 14) & 127;
    int b = g >> 21;
    int x1 = min(x + 1, NS - 1);
    int y1 = min(y + 1, NS - 1);

    const fx4* __restrict__ inb = in + (size_t)b * (NS * NS * NS);
    fx4 v00 = inb[(((size_t)x  * NS) + y ) * NS + z];   // (x ,y )
    fx4 v10 = inb[(((size_t)x1 * NS) + y ) * NS + z];   // (x1,y )
    fx4 v01 = inb[(((size_t)x  * NS) + y1) * NS + z];   // (x ,y1)
    fx4 v11 = inb[(((size_t)x1 * NS) + y1) * NS + z];   // (x1,y1)

    uint2 p00 = pack_h4(v00.x, v00.y, v00.z, v00.w);
    uint2 p10 = pack_h4(v10.x, v10.y, v10.z, v10.w);
    uint2 p01 = pack_h4(v01.x, v01.y, v01.z, v01.w);
    uint2 p11 = pack_h4(v11.x, v11.y, v11.z, v11.w);

    ux4 lo; lo.x = p00.x; lo.y = p00.y; lo.z = p10.x; lo.w = p10.y;
    ux4 hi; hi.x = p01.x; hi.y = p01.y; hi.z = p11.x; hi.w = p11.y;
    __builtin_nontemporal_store(lo, &tab[2 * (size_t)g + 0]);
    __builtin_nontemporal_store(hi, &tab[2 * (size_t)g + 1]);
}

// ---- resample helpers ------------------------------------------------
struct R4Setup {
    const ux4* e0;
    const ux4* e1;
    float wx, wy, wz;
};

__device__ __forceinline__ R4Setup setup_r4(
    const ux4* __restrict__ tb, float cx, float cy, float cz)
{
    const float fx = floorf(cx), fy = floorf(cy), fz = floorf(cz);
    R4Setup s;
    // boundary: floor<0 => both baked corners are voxel 0 -> force weight 0.
    // (z needs no fix: z0,z1 clamp independently; equal -> degenerate lerp.)
    s.wx = (fx < 0.f) ? 0.f : (cx - fx);
    s.wy = (fy < 0.f) ? 0.f : (cy - fy);
    s.wz = cz - fz;

    int x0 = max(0, min((int)fx, NS - 1));
    int y0 = max(0, min((int)fy, NS - 1));
    int z0 = max(0, min((int)fz,     NS - 1));
    int z1 = max(0, min((int)fz + 1, NS - 1));

    int ebase = ((x0 << 7) + y0) << 7;    // entry index of (x0,y0,z=0)
    s.e0 = tb + 2 * (size_t)(ebase + z0);
    s.e1 = tb + 2 * (size_t)(ebase + z1);
    return s;
}

__device__ __forceinline__ float4 finish_r4(
    const R4Setup& s, ux4 lo0, ux4 hi0, ux4 lo1, ux4 hi1)
{
    float4 c000 = unpack_h4(lo0.x, lo0.y), c100 = unpack_h4(lo0.z, lo0.w);
    float4 c010 = unpack_h4(hi0.x, hi0.y), c110 = unpack_h4(hi0.z, hi0.w);
    float4 c001 = unpack_h4(lo1.x, lo1.y), c101 = unpack_h4(lo1.z, lo1.w);
    float4 c011 = unpack_h4(hi1.x, hi1.y), c111 = unpack_h4(hi1.z, hi1.w);

    float4 d00 = f4_lerp(c000, c001, s.wz);   // (x0,y0)
    float4 d10 = f4_lerp(c100, c101, s.wz);   // (x1,y0)
    float4 d01 = f4_lerp(c010, c011, s.wz);   // (x0,y1)
    float4 d11 = f4_lerp(c110, c111, s.wz);   // (x1,y1)

    float4 ey0 = f4_lerp(d00, d01, s.wy);     // x0
    float4 ey1 = f4_lerp(d10, d11, s.wy);     // x1
    return f4_lerp(ey0, ey1, s.wx);
}

__device__ __forceinline__ void nt_store4(float4 v, fx4* p) {
    fx4 t; t.x = v.x; t.y = v.y; t.z = v.z; t.w = v.w;
    __builtin_nontemporal_store(t, p);
}

// ---- Resample: 4 points per thread (2 per batch) -> 16 gathers in flight
__global__ __launch_bounds__(256) void resample_r4(
    const ux4*   __restrict__ tab,
    const float* __restrict__ coords,
    fx4*         __restrict__ out)
{
    int i = blockIdx.x * 256 + threadIdx.x;     // 0 .. HPPB-1 (grid exact)
    const int i0 = i;                  // batch 0, first half
    const int i1 = i + HPPB;           // batch 0, second half
    const int i2 = i + PPB;            // batch 1, first half
    const int i3 = i + PPB + HPPB;     // batch 1, second half

    const ux4* tb0 = tab;
    const ux4* tb1 = tab + (size_t)ENTRIES_PER_BATCH * 2;

    R4Setup s0 = setup_r4(tb0, coords[3*i0+0], coords[3*i0+1], coords[3*i0+2]);
    R4Setup s1 = setup_r4(tb0, coords[3*i1+0], coords[3*i1+1], coords[3*i1+2]);
    R4Setup s2 = setup_r4(tb1, coords[3*i2+0], coords[3*i2+1], coords[3*i2+2]);
    R4Setup s3 = setup_r4(tb1, coords[3*i3+0], coords[3*i3+1], coords[3*i3+2]);

    // issue all 16 gathers before any use
    ux4 a_lo0 = s0.e0[0], a_hi0 = s0.e0[1], a_lo1 = s0.e1[0], a_hi1 = s0.e1[1];
    ux4 b_lo0 = s1.e0[0], b_hi0 = s1.e0[1], b_lo1 = s1.e1[0], b_hi1 = s1.e1[1];
    ux4 c_lo0 = s2.e0[0], c_hi0 = s2.e0[1], c_lo1 = s2.e1[0], c_hi1 = s2.e1[1];
    ux4 d_lo0 = s3.e0[0], d_hi0 = s3.e0[1], d_lo1 = s3.e1[0], d_hi1 = s3.e1[1];

    nt_store4(finish_r4(s0, a_lo0, a_hi0, a_lo1, a_hi1), &out[i0]);
    nt_store4(finish_r4(s1, b_lo0, b_hi0, b_lo1, b_hi1), &out[i1]);
    nt_store4(finish_r4(s2, c_lo0, c_hi0, c_lo1, c_hi1), &out[i2]);
    nt_store4(finish_r4(s3, d_lo0, d_hi0, d_lo1, d_hi1), &out[i3]);
}

// =====================================================================
// Fallback 1: fp16 2x2x2 bricks
// =====================================================================
__global__ __launch_bounds__(256) void repack_fp16_bricks(
    const fx4* __restrict__ in, uint2* __restrict__ bricks)
{
    int g = blockIdx.x * 256 + threadIdx.x;
    int t = g >> 3;
    int l = g & 7;
    int lx = (l >> 2) & 1, ly = (l >> 1) & 1, lz = l & 1;
    int b  = t >> 18;
    int r  = t & 262143;
    int x  = ((r >> 12) << 1) + lx;
    int y  = (((r >> 6) & 63) << 1) + ly;
    int z  = ((r & 63) << 1) + lz;

    fx4 v = __builtin_nontemporal_load(&in[(((size_t)b * NS + x) * NS + y) * NS + z]);
    bricks[g] = pack_h4(v.x, v.y, v.z, v.w);
}

__device__ __forceinline__ float4 vox_to_f4(uint2 v) {
    return unpack_h4(v.x, v.y);
}

__device__ __forceinline__ int brick_off(int x, int y, int z) {
    int bidx = (((x >> 1) * NB) + (y >> 1)) * NB + (z >> 1);
    return (bidx << 3) + ((x & 1) << 2) + ((y & 1) << 1) + (z & 1);
}

__global__ __launch_bounds__(256) void resample_bricks(
    const uint2* __restrict__ bricks,
    const float* __restrict__ coords,
    float4*      __restrict__ out)
{
    int idx = blockIdx.x * 256 + threadIdx.x;
    if (idx >= TOTAL) return;

    const float cx = coords[3 * idx + 0];
    const float cy = coords[3 * idx + 1];
    const float cz = coords[3 * idx + 2];
    const float fx = floorf(cx), fy = floorf(cy), fz = floorf(cz);
    const float wx = cx - fx, wy = cy - fy, wz = cz - fz;

    int x0 = max(0, min((int)fx,     NS - 1));
    int x1 = max(0, min((int)fx + 1, NS - 1));
    int y0 = max(0, min((int)fy,     NS - 1));
    int y1 = max(0, min((int)fy + 1, NS - 1));
    int z0 = max(0, min((int)fz,     NS - 1));
    int z1 = max(0, min((int)fz + 1, NS - 1));

    const uint2* __restrict__ wb =
        bricks + ((idx >= PPB) ? (size_t)BRICKS_PER_BATCH * 8 : 0);

    uint2 u000 = wb[brick_off(x0, y0, z0)], u001 = wb[brick_off(x0, y0, z1)];
    uint2 u010 = wb[brick_off(x0, y1, z0)], u011 = wb[brick_off(x0, y1, z1)];
    uint2 u100 = wb[brick_off(x1, y0, z0)], u101 = wb[brick_off(x1, y0, z1)];
    uint2 u110 = wb[brick_off(x1, y1, z0)], u111 = wb[brick_off(x1, y1, z1)];

    float4 c00 = f4_lerp(vox_to_f4(u000), vox_to_f4(u001), wz);
    float4 c01 = f4_lerp(vox_to_f4(u010), vox_to_f4(u011), wz);
    float4 c10 = f4_lerp(vox_to_f4(u100), vox_to_f4(u101), wz);
    float4 c11 = f4_lerp(vox_to_f4(u110), vox_to_f4(u111), wz);
    float4 c0 = f4_lerp(c00, c01, wy);
    float4 c1 = f4_lerp(c10, c11, wy);
    out[idx] = f4_lerp(c0, c1, wx);
}

// =====================================================================
// Fallback 2: direct fp32 gather (no workspace)
// =====================================================================
__global__ __launch_bounds__(256) void resample_direct(
    const float4* __restrict__ in,
    const float*  __restrict__ coords,
    float4*       __restrict__ out)
{
    int idx = blockIdx.x * blockDim.x + threadIdx.x;
    if (idx >= TOTAL) return;

    const float cx = coords[3 * idx + 0];
    const float cy = coords[3 * idx + 1];
    const float cz = coords[3 * idx + 2];
    const float fx = floorf(cx), fy = floorf(cy), fz = floorf(cz);
    const float wx = cx - fx, wy = cy - fy, wz = cz - fz;

    int x0 = max(0, min((int)fx,     NS - 1));
    int x1 = max(0, min((int)fx + 1, NS - 1));
    int y0 = max(0, min((int)fy,     NS - 1));
    int y1 = max(0, min((int)fy + 1, NS - 1));
    int z0 = max(0, min((int)fz,     NS - 1));
    int z1 = max(0, min((int)fz + 1, NS - 1));

    const int b = idx / PPB;
    const float4* __restrict__ inb = in + (size_t)b * (NS * NS * NS);
    const float4* r00 = inb + ((size_t)x0 * NS + y0) * NS;
    const float4* r01 = inb + ((size_t)x0 * NS + y1) * NS;
    const float4* r10 = inb + ((size_t)x1 * NS + y0) * NS;
    const float4* r11 = inb + ((size_t)x1 * NS + y1) * NS;

    float4 c00 = f4_lerp(r00[z0], r00[z1], wz);
    float4 c01 = f4_lerp(r01[z0], r01[z1], wz);
    float4 c10 = f4_lerp(r10[z0], r10[z1], wz);
    float4 c11 = f4_lerp(r11[z0], r11[z1], wz);
    float4 c0 = f4_lerp(c00, c01, wy);
    float4 c1 = f4_lerp(c10, c11, wy);
    out[idx] = f4_lerp(c0, c1, wx);
}

extern "C" void kernel_launch(void* const* d_in, const int* in_sizes, int n_in,
                              void* d_out, int out_size, void* d_ws, size_t ws_size,
                              hipStream_t stream) {
    const float* coords = (const float*)d_in[1];

    if (ws_size >= WS_R4) {
        ux4* tab = (ux4*)d_ws;
        int entries = BATCH * ENTRIES_PER_BATCH;          // 4194304
        build_r4_table<<<entries / 256, 256, 0, stream>>>((const fx4*)d_in[0], tab);
        // 4 points per thread; HPPB = 1728 * 256 exactly
        resample_r4<<<HPPB / 256, 256, 0, stream>>>(tab, coords, (fx4*)d_out);
    } else if (ws_size >= WS_BRICKS) {
        uint2* bricks = (uint2*)d_ws;
        int rp_threads = TOTAL_BRICKS * 8;                // 4194304
        repack_fp16_bricks<<<rp_threads / 256, 256, 0, stream>>>((const fx4*)d_in[0], bricks);
        resample_bricks<<<(TOTAL + 255) / 256, 256, 0, stream>>>(bricks, coords, (float4*)d_out);
    } else {
        resample_direct<<<(TOTAL + 255) / 256, 256, 0, stream>>>(
            (const float4*)d_in[0], coords, (float4*)d_out);
    }
}

// Round 16
// 197.005 us; speedup vs baseline: 1.0064x; 1.0064x over previous
//
#include <hip/hip_runtime.h>
#include <hip/hip_fp16.h>

// Problem constants (from reference)
#define BATCH 2
#define NS 128        // input spatial dim (X=Y=Z=128)
#define NB 64         // bricks per dim (fallback path)
#define ND 96         // output grid per spatial dim

constexpr int PPB   = ND * ND * ND;            // 884736 points per batch
constexpr int HPPB  = PPB / 2;                 // 442368
constexpr int TOTAL = BATCH * PPB;             // 1769472
constexpr int BRICKS_PER_BATCH = NB * NB * NB; // 262144
constexpr int TOTAL_BRICKS = BATCH * BRICKS_PER_BATCH;
constexpr size_t WS_BRICKS = (size_t)TOTAL_BRICKS * 64;            // 33.55 MB
constexpr int ENTRIES_PER_BATCH = NS * NS * NS;                    // 2097152
constexpr size_t WS_R4 = (size_t)BATCH * ENTRIES_PER_BATCH * 32;   // 134.2 MB

// native clang vector types: accepted by __builtin_nontemporal_*
typedef float        fx4 __attribute__((ext_vector_type(4)));
typedef unsigned int ux4 __attribute__((ext_vector_type(4)));

__device__ __forceinline__ float4 f4_lerp(float4 a, float4 b, float t) {
    float4 r;
    r.x = fmaf(b.x - a.x, t, a.x);
    r.y = fmaf(b.y - a.y, t, a.y);
    r.z = fmaf(b.z - a.z, t, a.z);
    r.w = fmaf(b.w - a.w, t, a.w);
    return r;
}

__device__ __forceinline__ uint2 pack_h4(float x, float y, float z, float w) {
    __half2 h0 = __float22half2_rn(make_float2(x, y));
    __half2 h1 = __float22half2_rn(make_float2(z, w));
    uint2 p;
    p.x = *(const unsigned int*)&h0;
    p.y = *(const unsigned int*)&h1;
    return p;
}

__device__ __forceinline__ float4 unpack_h4(unsigned int a, unsigned int b) {
    float2 f0 = __half22float2(*(const __half2*)&a);
    float2 f1 = __half22float2(*(const __half2*)&b);
    return make_float4(f0.x, f0.y, f1.x, f1.y);
}

// =====================================================================
// R4 table: per-voxel (x,y) 2x2 neighborhood, 32B/entry, Z FASTEST.
// entry(b,x,y,z): lo = [(x,y)|(x+1',y)], hi = [(x,y+1')|(x+1',y+1')]
// with x+1' = min(x+1,127), y+1' = min(y+1,127) (replicate baked in).
// Entry index == builder thread id: g = b*2^21 + x*2^14 + y*2^7 + z.
// =====================================================================
__global__ __launch_bounds__(256) void build_r4_table(
    const fx4* __restrict__ in, ux4* __restrict__ tab)
{
    int g = blockIdx.x * 256 + threadIdx.x;   // grid exact: 4194304 threads
    int z = g & 127;
    int y = (g >> 7) & 127;
    int x = (g >> 14) & 127;
    int b = g >> 21;
    int x1 = min(x + 1, NS - 1);
    int y1 = min(y + 1, NS - 1);

    const fx4* __restrict__ inb = in + (size_t)b * (NS * NS * NS);
    fx4 v00 = inb[(((size_t)x  * NS) + y ) * NS + z];   // (x ,y )
    fx4 v10 = inb[(((size_t)x1 * NS) + y ) * NS + z];   // (x1,y )
    fx4 v01 = inb[(((size_t)x  * NS) + y1) * NS + z];   // (x ,y1)
    fx4 v11 = inb[(((size_t)x1 * NS) + y1) * NS + z];   // (x1,y1)

    uint2 p00 = pack_h4(v00.x, v00.y, v00.z, v00.w);
    uint2 p10 = pack_h4(v10.x, v10.y, v10.z, v10.w);
    uint2 p01 = pack_h4(v01.x, v01.y, v01.z, v01.w);
    uint2 p11 = pack_h4(v11.x, v11.y, v11.z, v11.w);

    ux4 lo; lo.x = p00.x; lo.y = p00.y; lo.z = p10.x; lo.w = p10.y;
    ux4 hi; hi.x = p01.x; hi.y = p01.y; hi.z = p11.x; hi.w = p11.y;
    __builtin_nontemporal_store(lo, &tab[2 * (size_t)g + 0]);
    __builtin_nontemporal_store(hi, &tab[2 * (size_t)g + 1]);
}

// ---- resample helpers ------------------------------------------------
struct R4Setup {
    const ux4* e0;
    const ux4* e1;
    float wx, wy, wz;
};

__device__ __forceinline__ R4Setup setup_r4(
    const ux4* __restrict__ tb, float cx, float cy, float cz)
{
    const float fx = floorf(cx), fy = floorf(cy), fz = floorf(cz);
    R4Setup s;
    // boundary: floor<0 => both baked corners are voxel 0 -> force weight 0.
    // (z needs no fix: z0,z1 clamp independently; equal -> degenerate lerp.)
    s.wx = (fx < 0.f) ? 0.f : (cx - fx);
    s.wy = (fy < 0.f) ? 0.f : (cy - fy);
    s.wz = cz - fz;

    int x0 = max(0, min((int)fx, NS - 1));
    int y0 = max(0, min((int)fy, NS - 1));
    int z0 = max(0, min((int)fz,     NS - 1));
    int z1 = max(0, min((int)fz + 1, NS - 1));

    int ebase = ((x0 << 7) + y0) << 7;    // entry index of (x0,y0,z=0)
    s.e0 = tb + 2 * (size_t)(ebase + z0);
    s.e1 = tb + 2 * (size_t)(ebase + z1);
    return s;
}

__device__ __forceinline__ float4 finish_r4(
    const R4Setup& s, ux4 lo0, ux4 hi0, ux4 lo1, ux4 hi1)
{
    float4 c000 = unpack_h4(lo0.x, lo0.y), c100 = unpack_h4(lo0.z, lo0.w);
    float4 c010 = unpack_h4(hi0.x, hi0.y), c110 = unpack_h4(hi0.z, hi0.w);
    float4 c001 = unpack_h4(lo1.x, lo1.y), c101 = unpack_h4(lo1.z, lo1.w);
    float4 c011 = unpack_h4(hi1.x, hi1.y), c111 = unpack_h4(hi1.z, hi1.w);

    float4 d00 = f4_lerp(c000, c001, s.wz);   // (x0,y0)
    float4 d10 = f4_lerp(c100, c101, s.wz);   // (x1,y0)
    float4 d01 = f4_lerp(c010, c011, s.wz);   // (x0,y1)
    float4 d11 = f4_lerp(c110, c111, s.wz);   // (x1,y1)

    float4 ey0 = f4_lerp(d00, d01, s.wy);     // x0
    float4 ey1 = f4_lerp(d10, d11, s.wy);     // x1
    return f4_lerp(ey0, ey1, s.wx);
}

__device__ __forceinline__ void nt_store4(float4 v, fx4* p) {
    fx4 t; t.x = v.x; t.y = v.y; t.z = v.z; t.w = v.w;
    __builtin_nontemporal_store(t, p);
}

// ---- Resample: 2 points per thread, SAME batch (halved per-wave footprint)
// Thread j in [0, PPB): b = (j >= HPPB); p = j - b*HPPB;
// points: b*PPB + p and b*PPB + p + HPPB.
__global__ __launch_bounds__(256) void resample_r4(
    const ux4*   __restrict__ tab,
    const float* __restrict__ coords,
    fx4*         __restrict__ out)
{
    int j = blockIdx.x * 256 + threadIdx.x;     // 0 .. PPB-1 (grid exact)
    const int b  = (j >= HPPB) ? 1 : 0;
    const int p  = j - b * HPPB;
    const int i0 = b * PPB + p;
    const int i1 = i0 + HPPB;

    const ux4* tb = tab + (size_t)b * (ENTRIES_PER_BATCH * 2);

    R4Setup s0 = setup_r4(tb, coords[3*i0+0], coords[3*i0+1], coords[3*i0+2]);
    R4Setup s1 = setup_r4(tb, coords[3*i1+0], coords[3*i1+1], coords[3*i1+2]);

    // issue all 8 gathers before any use
    ux4 a_lo0 = s0.e0[0], a_hi0 = s0.e0[1], a_lo1 = s0.e1[0], a_hi1 = s0.e1[1];
    ux4 b_lo0 = s1.e0[0], b_hi0 = s1.e0[1], b_lo1 = s1.e1[0], b_hi1 = s1.e1[1];

    nt_store4(finish_r4(s0, a_lo0, a_hi0, a_lo1, a_hi1), &out[i0]);
    nt_store4(finish_r4(s1, b_lo0, b_hi0, b_lo1, b_hi1), &out[i1]);
}

// =====================================================================
// Fallback 1: fp16 2x2x2 bricks
// =====================================================================
__global__ __launch_bounds__(256) void repack_fp16_bricks(
    const fx4* __restrict__ in, uint2* __restrict__ bricks)
{
    int g = blockIdx.x * 256 + threadIdx.x;
    int t = g >> 3;
    int l = g & 7;
    int lx = (l >> 2) & 1, ly = (l >> 1) & 1, lz = l & 1;
    int b  = t >> 18;
    int r  = t & 262143;
    int x  = ((r >> 12) << 1) + lx;
    int y  = (((r >> 6) & 63) << 1) + ly;
    int z  = ((r & 63) << 1) + lz;

    fx4 v = __builtin_nontemporal_load(&in[(((size_t)b * NS + x) * NS + y) * NS + z]);
    bricks[g] = pack_h4(v.x, v.y, v.z, v.w);
}

__device__ __forceinline__ float4 vox_to_f4(uint2 v) {
    return unpack_h4(v.x, v.y);
}

__device__ __forceinline__ int brick_off(int x, int y, int z) {
    int bidx = (((x >> 1) * NB) + (y >> 1)) * NB + (z >> 1);
    return (bidx << 3) + ((x & 1) << 2) + ((y & 1) << 1) + (z & 1);
}

__global__ __launch_bounds__(256) void resample_bricks(
    const uint2* __restrict__ bricks,
    const float* __restrict__ coords,
    float4*      __restrict__ out)
{
    int idx = blockIdx.x * 256 + threadIdx.x;
    if (idx >= TOTAL) return;

    const float cx = coords[3 * idx + 0];
    const float cy = coords[3 * idx + 1];
    const float cz = coords[3 * idx + 2];
    const float fx = floorf(cx), fy = floorf(cy), fz = floorf(cz);
    const float wx = cx - fx, wy = cy - fy, wz = cz - fz;

    int x0 = max(0, min((int)fx,     NS - 1));
    int x1 = max(0, min((int)fx + 1, NS - 1));
    int y0 = max(0, min((int)fy,     NS - 1));
    int y1 = max(0, min((int)fy + 1, NS - 1));
    int z0 = max(0, min((int)fz,     NS - 1));
    int z1 = max(0, min((int)fz + 1, NS - 1));

    const uint2* __restrict__ wb =
        bricks + ((idx >= PPB) ? (size_t)BRICKS_PER_BATCH * 8 : 0);

    uint2 u000 = wb[brick_off(x0, y0, z0)], u001 = wb[brick_off(x0, y0, z1)];
    uint2 u010 = wb[brick_off(x0, y1, z0)], u011 = wb[brick_off(x0, y1, z1)];
    uint2 u100 = wb[brick_off(x1, y0, z0)], u101 = wb[brick_off(x1, y0, z1)];
    uint2 u110 = wb[brick_off(x1, y1, z0)], u111 = wb[brick_off(x1, y1, z1)];

    float4 c00 = f4_lerp(vox_to_f4(u000), vox_to_f4(u001), wz);
    float4 c01 = f4_lerp(vox_to_f4(u010), vox_to_f4(u011), wz);
    float4 c10 = f4_lerp(vox_to_f4(u100), vox_to_f4(u101), wz);
    float4 c11 = f4_lerp(vox_to_f4(u110), vox_to_f4(u111), wz);
    float4 c0 = f4_lerp(c00, c01, wy);
    float4 c1 = f4_lerp(c10, c11, wy);
    out[idx] = f4_lerp(c0, c1, wx);
}

// =====================================================================
// Fallback 2: direct fp32 gather (no workspace)
// =====================================================================
__global__ __launch_bounds__(256) void resample_direct(
    const float4* __restrict__ in,
    const float*  __restrict__ coords,
    float4*       __restrict__ out)
{
    int idx = blockIdx.x * blockDim.x + threadIdx.x;
    if (idx >= TOTAL) return;

    const float cx = coords[3 * idx + 0];
    const float cy = coords[3 * idx + 1];
    const float cz = coords[3 * idx + 2];
    const float fx = floorf(cx), fy = floorf(cy), fz = floorf(cz);
    const float wx = cx - fx, wy = cy - fy, wz = cz - fz;

    int x0 = max(0, min((int)fx,     NS - 1));
    int x1 = max(0, min((int)fx + 1, NS - 1));
    int y0 = max(0, min((int)fy,     NS - 1));
    int y1 = max(0, min((int)fy + 1, NS - 1));
    int z0 = max(0, min((int)fz,     NS - 1));
    int z1 = max(0, min((int)fz + 1, NS - 1));

    const int b = idx / PPB;
    const float4* __restrict__ inb = in + (size_t)b * (NS * NS * NS);
    const float4* r00 = inb + ((size_t)x0 * NS + y0) * NS;
    const float4* r01 = inb + ((size_t)x0 * NS + y1) * NS;
    const float4* r10 = inb + ((size_t)x1 * NS + y0) * NS;
    const float4* r11 = inb + ((size_t)x1 * NS + y1) * NS;

    float4 c00 = f4_lerp(r00[z0], r00[z1], wz);
    float4 c01 = f4_lerp(r01[z0], r01[z1], wz);
    float4 c10 = f4_lerp(r10[z0], r10[z1], wz);
    float4 c11 = f4_lerp(r11[z0], r11[z1], wz);
    float4 c0 = f4_lerp(c00, c01, wy);
    float4 c1 = f4_lerp(c10, c11, wy);
    out[idx] = f4_lerp(c0, c1, wx);
}

extern "C" void kernel_launch(void* const* d_in, const int* in_sizes, int n_in,
                              void* d_out, int out_size, void* d_ws, size_t ws_size,
                              hipStream_t stream) {
    const float* coords = (const float*)d_in[1];

    if (ws_size >= WS_R4) {
        ux4* tab = (ux4*)d_ws;
        int entries = BATCH * ENTRIES_PER_BATCH;          // 4194304
        build_r4_table<<<entries / 256, 256, 0, stream>>>((const fx4*)d_in[0], tab);
        // 2 same-batch points per thread; PPB = 3456 * 256 exactly
        resample_r4<<<PPB / 256, 256, 0, stream>>>(tab, coords, (fx4*)d_out);
    } else if (ws_size >= WS_BRICKS) {
        uint2* bricks = (uint2*)d_ws;
        int rp_threads = TOTAL_BRICKS * 8;                // 4194304
        repack_fp16_bricks<<<rp_threads / 256, 256, 0, stream>>>((const fx4*)d_in[0], bricks);
        resample_bricks<<<(TOTAL + 255) / 256, 256, 0, stream>>>(bricks, coords, (float4*)d_out);
    } else {
        resample_direct<<<(TOTAL + 255) / 256, 256, 0, stream>>>(
            (const float4*)d_in[0], coords, (float4*)d_out);
    }
}